// Round 1
// baseline (14164.980 us; speedup 1.0000x reference)
//
#include <hip/hip_runtime.h>
#include <cstdint>

#define DEVI __device__ __forceinline__

typedef unsigned short u16;
typedef __bf16 bf16x8 __attribute__((ext_vector_type(8)));
typedef float f32x4 __attribute__((ext_vector_type(4)));

// B=32, T=128 (127 decode steps), V=32000, E=256, U=AU=M=1024, S=128
#define NB 32
#define NT 127
#define NV 32000
#define NE 256
#define NU 1024

DEVI float b2f(u16 h){ union{unsigned u; float f;} v; v.u = ((unsigned)h)<<16; return v.f; }
DEVI u16 f2b(float f){ union{float f; unsigned u;} v; v.f=f; unsigned u=v.u;
                       return (u16)((u + 0x7fffu + ((u>>16)&1u))>>16); }
DEVI float sigm(float x){ return 1.f/(1.f+__expf(-x)); }
DEVI float tanh_(float x){ return 1.f - 2.f/(1.f+__expf(2.f*x)); }

// ---------------- small conversion kernels ----------------
__global__ void k_conv(const float* __restrict__ s, u16* __restrict__ d, int n){
  for (int i = blockIdx.x*256 + threadIdx.x; i < n; i += gridDim.x*256) d[i] = f2b(s[i]);
}
__global__ void k_split(const float* __restrict__ s, u16* __restrict__ dh, u16* __restrict__ dl, int n){
  for (int i = blockIdx.x*256 + threadIdx.x; i < n; i += gridDim.x*256){
    float v = s[i]; u16 hi = f2b(v); dh[i]=hi; dl[i]=f2b(v-b2f(hi));
  }
}
__global__ void k_gather(const int* __restrict__ toks, const float* __restrict__ emb, u16* __restrict__ x){
  int i = blockIdx.x*256 + threadIdx.x;
  if (i >= NB*NT*NE) return;
  int bt = i>>8, e = i&255;
  int b = bt/NT, t = bt - b*NT;
  int tok = toks[b*128 + t];                 // dec_in = output_batch[:, :-1]
  x[i] = f2b(emb[(size_t)tok*NE + e]);
}
// transpose f32 (R x C, row stride rs) -> bf16 hi/lo (C x dstStride) at dst[c*dstStride+dstOff+r]
__global__ void k_transpose(const float* __restrict__ src, int rs,
                            u16* __restrict__ dh, u16* __restrict__ dl,
                            int dstStride, int dstOff){
  __shared__ float tile[32][33];
  int tc = blockIdx.x*32, tr = blockIdx.y*32;
  int tx = threadIdx.x & 31, ty = threadIdx.x >> 5;
  #pragma unroll
  for (int rr=0; rr<4; ++rr){
    int r = ty + rr*8;
    tile[r][tx] = src[(size_t)(tr+r)*rs + tc + tx];
  }
  __syncthreads();
  #pragma unroll
  for (int rr=0; rr<4; ++rr){
    int cl = ty + rr*8;
    float v = tile[tx][cl];
    u16 hi = f2b(v);
    size_t o = (size_t)(tc+cl)*dstStride + dstOff + tr + tx;
    dh[o] = hi;
    if (dl) dl[o] = f2b(v - b2f(hi));
  }
}

// ---------------- generic 64x64-tile bf16 MFMA GEMM ----------------
// C[M,N] = A[M,K] * Bt[N,K]^T (+bias). OUTF=0 -> f32 C, 1 -> bf16 C.
template<int OUTF, int BIAS>
__global__ __launch_bounds__(256) void k_gemm64(
    const u16* __restrict__ A, int lda,
    const u16* __restrict__ Bt, int ldb,
    float* __restrict__ Cf, u16* __restrict__ Cb, int ldc,
    const float* __restrict__ bias, int M, int K)
{
  __shared__ __align__(16) u16 As[64][40];
  __shared__ __align__(16) u16 Bs[64][40];
  int n0 = blockIdx.x*64, m0 = blockIdx.y*64;
  int tid = threadIdx.x, lane = tid & 63, w = tid>>6;
  int lr = tid>>2, lk = (tid&3)*8;
  f32x4 acc[4] = {};
  for (int kk=0; kk<K; kk+=32){
    uint4 av = make_uint4(0,0,0,0);
    int row = m0 + lr;
    if (row < M) av = *(const uint4*)(A + (size_t)row*lda + kk + lk);
    *(uint4*)(&As[lr][lk]) = av;
    uint4 bv = *(const uint4*)(Bt + (size_t)(n0+lr)*ldb + kk + lk);
    *(uint4*)(&Bs[lr][lk]) = bv;
    __syncthreads();
    bf16x8 af = *(const bf16x8*)(&As[w*16 + (lane&15)][(lane>>4)*8]);
    #pragma unroll
    for (int ni=0; ni<4; ++ni){
      bf16x8 bfr = *(const bf16x8*)(&Bs[ni*16 + (lane&15)][(lane>>4)*8]);
      acc[ni] = __builtin_amdgcn_mfma_f32_16x16x32_bf16(af, bfr, acc[ni], 0,0,0);
    }
    __syncthreads();
  }
  #pragma unroll
  for (int ni=0; ni<4; ++ni){
    #pragma unroll
    for (int r=0; r<4; ++r){
      int row = m0 + w*16 + (lane>>4)*4 + r;
      int col = n0 + ni*16 + (lane&15);
      if (row < M){
        float v = acc[ni][r];
        if (BIAS) v += bias[col];
        if (OUTF==0) Cf[(size_t)row*ldc + col] = v;
        else         Cb[(size_t)row*ldc + col] = f2b(v);
      }
    }
  }
}

// ---------------- skinny (M=32) split-precision MFMA GEMM ----------------
// acc = A*W with A=(Ah+Al), W=(Wh+Wl); 3-term MFMA => ~f32 accuracy.
// A rows b<32; k<1024 reads A0, k>=1024 reads A1. Wt is (Ncols x K) row-major.
// MODE 0: out f32 (q). MODE 1: out bf16 hi/lo (attn row stride sOut).
// MODE 2: 4 gates (cols g*1024+u0+u), + xW base add, LSTM gate epilogue.
template<int MODE>
__global__ __launch_bounds__(256) void k_skinny(
    const u16* __restrict__ A0h, const u16* __restrict__ A0l, int sA0,
    const u16* __restrict__ A1h, const u16* __restrict__ A1l, int sA1,
    const u16* __restrict__ Wh, const u16* __restrict__ Wl, int K,
    float* __restrict__ outF,
    u16* __restrict__ outH, u16* __restrict__ outL, int sOut,
    const u16* __restrict__ xW, int sXW, float* __restrict__ cbuf,
    u16* __restrict__ hH, u16* __restrict__ hL)
{
  __shared__ float zs[4][32][64];
  int tid = threadIdx.x, lane = tid&63, wv = tid>>6;
  int Kq = K >> 2;
  int k0 = wv * Kq;
  int u0 = 0, n0 = 0;
  if (MODE==2) u0 = blockIdx.x*16; else n0 = blockIdx.x*64;
  f32x4 acc[8] = {};
  int ko = (lane>>4)*8;
  int l15 = lane&15;
  for (int kk = k0; kk < k0 + Kq; kk += 32){
    const u16 *Ah, *Al; int kl, st;
    if (kk < 1024){ Ah = A0h; Al = A0l; kl = kk;       st = sA0; }
    else          { Ah = A1h; Al = A1l; kl = kk-1024;  st = sA1; }
    bf16x8 a0h = *(const bf16x8*)(Ah + (size_t)l15*st        + kl + ko);
    bf16x8 a1h = *(const bf16x8*)(Ah + (size_t)(16+l15)*st   + kl + ko);
    bf16x8 a0l = *(const bf16x8*)(Al + (size_t)l15*st        + kl + ko);
    bf16x8 a1l = *(const bf16x8*)(Al + (size_t)(16+l15)*st   + kl + ko);
    #pragma unroll
    for (int j=0; j<4; ++j){
      int wrow = (MODE==2) ? (j*1024 + u0 + l15) : (n0 + j*16 + l15);
      bf16x8 bh = *(const bf16x8*)(Wh + (size_t)wrow*K + kk + ko);
      bf16x8 bl = *(const bf16x8*)(Wl + (size_t)wrow*K + kk + ko);
      acc[j*2]   = __builtin_amdgcn_mfma_f32_16x16x32_bf16(a0h, bl, acc[j*2],   0,0,0);
      acc[j*2]   = __builtin_amdgcn_mfma_f32_16x16x32_bf16(a0l, bh, acc[j*2],   0,0,0);
      acc[j*2]   = __builtin_amdgcn_mfma_f32_16x16x32_bf16(a0h, bh, acc[j*2],   0,0,0);
      acc[j*2+1] = __builtin_amdgcn_mfma_f32_16x16x32_bf16(a1h, bl, acc[j*2+1], 0,0,0);
      acc[j*2+1] = __builtin_amdgcn_mfma_f32_16x16x32_bf16(a1l, bh, acc[j*2+1], 0,0,0);
      acc[j*2+1] = __builtin_amdgcn_mfma_f32_16x16x32_bf16(a1h, bh, acc[j*2+1], 0,0,0);
    }
  }
  #pragma unroll
  for (int j=0; j<4; ++j)
    #pragma unroll
    for (int m=0; m<2; ++m)
      #pragma unroll
      for (int r=0; r<4; ++r){
        int b = m*16 + (lane>>4)*4 + r;
        zs[wv][b][j*16 + l15] = acc[j*2+m][r];
      }
  __syncthreads();
  if (MODE==0){
    for (int pi = tid; pi < 2048; pi += 256){
      int b = pi>>6, cl = pi&63;
      float v = zs[0][b][cl]+zs[1][b][cl]+zs[2][b][cl]+zs[3][b][cl];
      outF[b*NU + n0 + cl] = v;
    }
  } else if (MODE==1){
    for (int pi = tid; pi < 2048; pi += 256){
      int b = pi>>6, cl = pi&63;
      float v = zs[0][b][cl]+zs[1][b][cl]+zs[2][b][cl]+zs[3][b][cl];
      u16 hi = f2b(v);
      size_t o = (size_t)b*sOut + n0 + cl;
      outH[o] = hi; outL[o] = f2b(v - b2f(hi));
    }
  } else {
    for (int pi = tid; pi < 512; pi += 256){
      int b = pi>>4, u = pi&15;
      float zg[4];
      #pragma unroll
      for (int g=0; g<4; ++g){
        int cl = g*16 + u;
        float v = zs[0][b][cl]+zs[1][b][cl]+zs[2][b][cl]+zs[3][b][cl];
        zg[g] = v + b2f(xW[(size_t)b*sXW + g*1024 + u0 + u]);
      }
      float i_ = sigm(zg[0]), f_ = sigm(zg[1]), g_ = tanh_(zg[2]), o_ = sigm(zg[3]);
      int ci = b*NU + u0 + u;
      float cn = f_*cbuf[ci] + i_*g_;
      float h  = o_*tanh_(cn);
      cbuf[ci] = cn;
      u16 hi = f2b(h); hH[ci] = hi; hL[ci] = f2b(h - b2f(hi));
    }
  }
}

// ---------------- fused score -> softmax -> ctx (one block per b) ----------------
__global__ __launch_bounds__(1024) void k_score_ctx(
    const u16* __restrict__ keys, const float* __restrict__ q,
    const float* __restrict__ v_att, const float* __restrict__ a,
    u16* __restrict__ ctxH, u16* __restrict__ ctxL)
{
  __shared__ float qs[NU], vs[NU], sc[128], alig[128];
  int b = blockIdx.x, tid = threadIdx.x, lane = tid&63, wv = tid>>6;
  qs[tid] = q[b*NU + tid];
  vs[tid] = v_att[tid];
  __syncthreads();
  #pragma unroll
  for (int si=0; si<8; ++si){
    int s = wv*8 + si;
    const u16* kp = keys + (size_t)(b*128 + s)*NU;
    float p = 0.f;
    #pragma unroll
    for (int j=0; j<16; ++j){
      int ai = lane + 64*j;
      p += vs[ai] * tanh_(b2f(kp[ai]) + qs[ai]);
    }
    #pragma unroll
    for (int off=32; off; off>>=1) p += __shfl_xor(p, off);
    if (lane==0) sc[s] = p;
  }
  __syncthreads();
  if (wv==0){
    float s0 = sc[lane], s1 = sc[lane+64];
    float m = fmaxf(s0, s1);
    #pragma unroll
    for (int off=32; off; off>>=1) m = fmaxf(m, __shfl_xor(m, off));
    float e0 = __expf(s0-m), e1 = __expf(s1-m);
    float sum = e0+e1;
    #pragma unroll
    for (int off=32; off; off>>=1) sum += __shfl_xor(sum, off);
    float inv = 1.f/sum;
    alig[lane] = e0*inv; alig[lane+64] = e1*inv;
  }
  __syncthreads();
  int col = tid;
  float accv = 0.f;
  const float* ap = a + (size_t)b*128*NU + col;
  #pragma unroll 8
  for (int s=0; s<128; ++s) accv += alig[s]*ap[(size_t)s*NU];
  u16 hi = f2b(accv);
  ctxH[b*NU+col] = hi;
  ctxL[b*NU+col] = f2b(accv - b2f(hi));
}

// ---------------- host ----------------
extern "C" void kernel_launch(void* const* d_in, const int* in_sizes, int n_in,
                              void* d_out, int out_size, void* d_ws, size_t ws_size,
                              hipStream_t stream)
{
  (void)in_sizes; (void)n_in; (void)out_size; (void)ws_size;
  const int*   toks  = (const int*)  d_in[0];
  const float* a_in  = (const float*)d_in[1];
  const float* a_tx  = (const float*)d_in[2];
  const float* c_tx  = (const float*)d_in[3];
  const float* emb   = (const float*)d_in[4];
  const float* W_k   = (const float*)d_in[5];
  const float* W_r   = (const float*)d_in[6];
  const float* bvec  = (const float*)d_in[7];
  const float* W_m   = (const float*)d_in[8];
  const float* W_q   = (const float*)d_in[9];
  const float* v_att = (const float*)d_in[10];
  const float* W_a   = (const float*)d_in[11];
  const float* W_o   = (const float*)d_in[12];
  const float* b_o   = (const float*)d_in[13];
  float* out = (float*)d_out;

  char* p = (char*)d_ws;
  auto alloc = [&](size_t bytes)->char*{ char* r = p; p += (bytes + 255) & ~(size_t)255; return r; };

  u16* WkrH = (u16*)alloc((size_t)4096*2048*2);
  u16* WkrL = (u16*)alloc((size_t)4096*2048*2);
  u16* WqH  = (u16*)alloc((size_t)1024*1024*2);
  u16* WqL  = (u16*)alloc((size_t)1024*1024*2);
  u16* WaH  = (u16*)alloc((size_t)1024*2048*2);
  u16* WaL  = (u16*)alloc((size_t)1024*2048*2);
  u16* WmH  = (u16*)alloc((size_t)1024*1024*2);
  u16* WoH  = (u16*)alloc((size_t)NV*1024*2);
  u16* WkxH = (u16*)alloc((size_t)4096*256*2);
  u16* aB   = (u16*)alloc((size_t)NB*128*NU*2);
  u16* keysB= (u16*)alloc((size_t)NB*128*NU*2);
  u16* xB   = (u16*)alloc((size_t)NB*NT*NE*2);
  u16* xWb  = (u16*)alloc((size_t)NB*NT*4096*2);
  u16* outsH= (u16*)alloc((size_t)NB*NT*NU*2);
  u16* outsL= (u16*)alloc((size_t)NB*NT*NU*2);
  u16* hH0  = (u16*)alloc((size_t)NB*NU*2);
  u16* hL0  = (u16*)alloc((size_t)NB*NU*2);
  u16* hH1  = (u16*)alloc((size_t)NB*NU*2);
  u16* hL1  = (u16*)alloc((size_t)NB*NU*2);
  u16* hiniH= (u16*)alloc((size_t)NB*NU*2);
  u16* hiniL= (u16*)alloc((size_t)NB*NU*2);
  u16* azero= (u16*)alloc((size_t)NB*NU*2);
  float* cbuf=(float*)alloc((size_t)NB*NU*4);
  float* qf  =(float*)alloc((size_t)NB*NU*4);
  u16* ctxH = (u16*)alloc((size_t)NB*NU*2);
  u16* ctxL = (u16*)alloc((size_t)NB*NU*2);
  u16* hbH[2] = {hH0, hH1};
  u16* hbL[2] = {hL0, hL1};

  // ---- init & weight prep ----
  hipMemsetAsync(azero, 0, (size_t)NB*NU*2, stream);
  hipMemcpyAsync(cbuf, c_tx, (size_t)NB*NU*4, hipMemcpyDeviceToDevice, stream);
  k_split<<<128,256,0,stream>>>(a_tx, hiniH, hiniL, NB*NU);
  k_gather<<<(NB*NT*NE)/256,256,0,stream>>>(toks, emb, xB);
  k_conv<<<2048,256,0,stream>>>(a_in, aB, NB*128*NU);
  // W_k rows 256..1279 (attn part) -> Wkr cols, k 0..1023
  k_transpose<<<dim3(128,32),256,0,stream>>>(W_k + (size_t)256*4096, 4096, WkrH, WkrL, 2048, 0);
  // W_r -> Wkr cols, k 1024..2047
  k_transpose<<<dim3(128,32),256,0,stream>>>(W_r, 4096, WkrH, WkrL, 2048, 1024);
  k_transpose<<<dim3(32,32),256,0,stream>>>(W_q, 1024, WqH, WqL, 1024, 0);
  k_transpose<<<dim3(32,64),256,0,stream>>>(W_a, 1024, WaH, WaL, 2048, 0);
  k_transpose<<<dim3(32,32),256,0,stream>>>(W_m, 1024, WmH, nullptr, 1024, 0);
  k_transpose<<<dim3(1000,32),256,0,stream>>>(W_o, NV, WoH, nullptr, 1024, 0);
  k_transpose<<<dim3(128,8),256,0,stream>>>(W_k, 4096, WkxH, nullptr, 256, 0);

  // keys = a @ W_m  (4096 x 1024, K=1024) -> bf16
  k_gemm64<1,0><<<dim3(16,64),256,0,stream>>>(aB, 1024, WmH, 1024, nullptr, keysB, 1024, nullptr, 4096, 1024);
  // xW = x @ W_k[0:256] + b  (4064 x 4096, K=256) -> bf16
  k_gemm64<1,1><<<dim3(64,64),256,0,stream>>>(xB, 256, WkxH, 256, nullptr, xWb, 4096, bvec, NB*NT, 256);

  // ---- recurrence ----
  for (int t=0; t<NT; ++t){
    const u16 *attnH, *attnL; int sAttn;
    if (t==0){ attnH = azero; attnL = azero; sAttn = NU; }
    else { attnH = outsH + (size_t)(t-1)*NU; attnL = outsL + (size_t)(t-1)*NU; sAttn = NT*NU; }
    const u16* hinH = (t==0) ? hiniH : hbH[(t-1)&1];
    const u16* hinL = (t==0) ? hiniL : hbL[(t-1)&1];
    u16* houtH = hbH[t&1];
    u16* houtL = hbL[t&1];
    // phase a: z = attn@Wk_attn + h@W_r (+xW incl. bias) -> gates -> h,c
    k_skinny<2><<<64,256,0,stream>>>(attnH, attnL, sAttn, hinH, hinL, NU,
        WkrH, WkrL, 2048, nullptr, nullptr, nullptr, 0,
        xWb + (size_t)t*4096, NT*4096, cbuf, houtH, houtL);
    // phase b: q = h @ W_q
    k_skinny<0><<<16,256,0,stream>>>(houtH, houtL, NU, houtH, houtL, NU,
        WqH, WqL, 1024, qf, nullptr, nullptr, 0, nullptr, 0, nullptr, nullptr, nullptr);
    // phase c: score -> softmax -> ctx
    k_score_ctx<<<NB,1024,0,stream>>>(keysB, qf, v_att, a_in, ctxH, ctxL);
    // phase d: attn_new = [h, ctx] @ W_a -> outs[t]
    k_skinny<1><<<16,256,0,stream>>>(houtH, houtL, NU, ctxH, ctxL, NU,
        WaH, WaL, 2048, nullptr, outsH + (size_t)t*NU, outsL + (size_t)t*NU, NT*NU,
        nullptr, 0, nullptr, nullptr, nullptr);
  }

  // ---- logits = outs @ W_o + b_o  (4064 x 32000, K=1024) ----
  k_gemm64<0,1><<<dim3(NV/64,64),256,0,stream>>>(outsH, 1024, WoH, 1024, out, nullptr, NV, b_o, NB*NT, 1024);
}

// Round 2
// 7672.386 us; speedup vs baseline: 1.8462x; 1.8462x over previous
//
#include <hip/hip_runtime.h>
#include <cstdint>

#define DEVI __device__ __forceinline__

typedef unsigned short u16;
typedef __bf16 bf16x8 __attribute__((ext_vector_type(8)));
typedef u16 u16x8 __attribute__((ext_vector_type(8)));
typedef float f32x4 __attribute__((ext_vector_type(4)));

// B=32, T=128 (127 decode steps), V=32000, E=256, U=AU=M=1024, S=128
#define NB 32
#define NT 127
#define NV 32000
#define NE 256
#define NU 1024

DEVI float b2f(u16 h){ union{unsigned u; float f;} v; v.u = ((unsigned)h)<<16; return v.f; }
DEVI u16 f2b(float f){ union{float f; unsigned u;} v; v.f=f; unsigned u=v.u;
                       return (u16)((u + 0x7fffu + ((u>>16)&1u))>>16); }
DEVI float sigm(float x){ return 1.f/(1.f+__expf(-x)); }
DEVI float tanh_(float x){ return 1.f - 2.f/(1.f+__expf(2.f*x)); }
#define MFMA __builtin_amdgcn_mfma_f32_16x16x32_bf16

// ---------------- small conversion kernels ----------------
__global__ void k_conv(const float* __restrict__ s, u16* __restrict__ d, int n){
  for (int i = blockIdx.x*256 + threadIdx.x; i < n; i += gridDim.x*256) d[i] = f2b(s[i]);
}
__global__ void k_split(const float* __restrict__ s, u16* __restrict__ dh, u16* __restrict__ dl, int n){
  for (int i = blockIdx.x*256 + threadIdx.x; i < n; i += gridDim.x*256){
    float v = s[i]; u16 hi = f2b(v); dh[i]=hi; dl[i]=f2b(v-b2f(hi));
  }
}
__global__ void k_gather(const int* __restrict__ toks, const float* __restrict__ emb, u16* __restrict__ x){
  int i = blockIdx.x*256 + threadIdx.x;
  if (i >= NB*NT*NE) return;
  int bt = i>>8, e = i&255;
  int b = bt/NT, t = bt - b*NT;
  int tok = toks[b*128 + t];                 // dec_in = output_batch[:, :-1]
  x[i] = f2b(emb[(size_t)tok*NE + e]);
}
// transpose f32 (R x C, row stride rs) -> bf16 hi/lo (C x dstStride) at dst[c*dstStride+dstOff+r]
__global__ void k_transpose(const float* __restrict__ src, int rs,
                            u16* __restrict__ dh, u16* __restrict__ dl,
                            int dstStride, int dstOff){
  __shared__ float tile[32][33];
  int tc = blockIdx.x*32, tr = blockIdx.y*32;
  int tx = threadIdx.x & 31, ty = threadIdx.x >> 5;
  #pragma unroll
  for (int rr=0; rr<4; ++rr){
    int r = ty + rr*8;
    tile[r][tx] = src[(size_t)(tr+r)*rs + tc + tx];
  }
  __syncthreads();
  #pragma unroll
  for (int rr=0; rr<4; ++rr){
    int cl = ty + rr*8;
    float v = tile[tx][cl];
    u16 hi = f2b(v);
    size_t o = (size_t)(tc+cl)*dstStride + dstOff + tr + tx;
    dh[o] = hi;
    if (dl) dl[o] = f2b(v - b2f(hi));
  }
}

// ---------------- generic 64x64-tile bf16 MFMA GEMM (prep only) ----------------
template<int OUTF, int BIAS>
__global__ __launch_bounds__(256) void k_gemm64(
    const u16* __restrict__ A, int lda,
    const u16* __restrict__ Bt, int ldb,
    float* __restrict__ Cf, u16* __restrict__ Cb, int ldc,
    const float* __restrict__ bias, int M, int K)
{
  __shared__ __align__(16) u16 As[64][40];
  __shared__ __align__(16) u16 Bs[64][40];
  int n0 = blockIdx.x*64, m0 = blockIdx.y*64;
  int tid = threadIdx.x, lane = tid & 63, w = tid>>6;
  int lr = tid>>2, lk = (tid&3)*8;
  f32x4 acc[4] = {};
  for (int kk=0; kk<K; kk+=32){
    uint4 av = make_uint4(0,0,0,0);
    int row = m0 + lr;
    if (row < M) av = *(const uint4*)(A + (size_t)row*lda + kk + lk);
    *(uint4*)(&As[lr][lk]) = av;
    uint4 bv = *(const uint4*)(Bt + (size_t)(n0+lr)*ldb + kk + lk);
    *(uint4*)(&Bs[lr][lk]) = bv;
    __syncthreads();
    bf16x8 af = *(const bf16x8*)(&As[w*16 + (lane&15)][(lane>>4)*8]);
    #pragma unroll
    for (int ni=0; ni<4; ++ni){
      bf16x8 bfr = *(const bf16x8*)(&Bs[ni*16 + (lane&15)][(lane>>4)*8]);
      acc[ni] = MFMA(af, bfr, acc[ni], 0,0,0);
    }
    __syncthreads();
  }
  #pragma unroll
  for (int ni=0; ni<4; ++ni){
    #pragma unroll
    for (int r=0; r<4; ++r){
      int row = m0 + w*16 + (lane>>4)*4 + r;
      int col = n0 + ni*16 + (lane&15);
      if (row < M){
        float v = acc[ni][r];
        if (BIAS) v += bias[col];
        if (OUTF==0) Cf[(size_t)row*ldc + col] = v;
        else         Cb[(size_t)row*ldc + col] = f2b(v);
      }
    }
  }
}

// ---------------- phase A: z = attn@Wk_a + h@W_r (+xW) -> gates -> h,c ----------------
// grid 256 blocks (4 u's x 4 gates each), 512 threads (8 waves split K=2048)
__global__ __launch_bounds__(512) void k_stepA(
    const u16* __restrict__ attnH, const u16* __restrict__ attnL, long sAttn,
    const u16* __restrict__ hHin, const u16* __restrict__ hLin,
    const u16* __restrict__ WH, const u16* __restrict__ WL,
    const u16* __restrict__ xW, long sXW,
    float* __restrict__ cbuf, u16* __restrict__ hH, u16* __restrict__ hL)
{
  __shared__ float zs[8][32][16];
  int tid = threadIdx.x, lane = tid&63, wv = tid>>6;
  int u0 = blockIdx.x*4, l15 = lane&15, ko = (lane>>4)*8;
  int wrow = (l15>>2)*1024 + u0 + (l15&3);
  const u16* wh = WH + (size_t)wrow*2048;
  const u16* wl = WL + (size_t)wrow*2048;
  const u16 *Ah, *Al; long st; int kb;
  if (wv < 4){ Ah = attnH; Al = attnL; st = sAttn; kb = wv*256; }
  else       { Ah = hHin;  Al = hLin;  st = 1024;  kb = wv*256 - 1024; }
  f32x4 acc0 = {}, acc1 = {};
  #pragma unroll
  for (int ki=0; ki<8; ++ki){
    int kw = wv*256 + ki*32 + ko;   // k for W
    int kl = kb + ki*32 + ko;       // k for A
    bf16x8 a0h = *(const bf16x8*)(Ah + (size_t)l15*st + kl);
    bf16x8 a1h = *(const bf16x8*)(Ah + (size_t)(l15+16)*st + kl);
    bf16x8 a0l = *(const bf16x8*)(Al + (size_t)l15*st + kl);
    bf16x8 a1l = *(const bf16x8*)(Al + (size_t)(l15+16)*st + kl);
    bf16x8 bh = *(const bf16x8*)(wh + kw);
    bf16x8 bl = *(const bf16x8*)(wl + kw);
    acc0 = MFMA(a0h, bl, acc0, 0,0,0);
    acc0 = MFMA(a0l, bh, acc0, 0,0,0);
    acc0 = MFMA(a0h, bh, acc0, 0,0,0);
    acc1 = MFMA(a1h, bl, acc1, 0,0,0);
    acc1 = MFMA(a1l, bh, acc1, 0,0,0);
    acc1 = MFMA(a1h, bh, acc1, 0,0,0);
  }
  #pragma unroll
  for (int r=0; r<4; ++r){
    zs[wv][(lane>>4)*4 + r][l15]      = acc0[r];
    zs[wv][16 + (lane>>4)*4 + r][l15] = acc1[r];
  }
  __syncthreads();
  if (tid < 128){
    int b = tid>>2, du = tid&3;
    float zg[4];
    #pragma unroll
    for (int g=0; g<4; ++g){
      float v = 0.f;
      #pragma unroll
      for (int w=0; w<8; ++w) v += zs[w][b][g*4+du];
      zg[g] = v + b2f(xW[(size_t)b*sXW + g*1024 + u0 + du]);
    }
    float i_ = sigm(zg[0]), f_ = sigm(zg[1]), g_ = tanh_(zg[2]), o_ = sigm(zg[3]);
    int ci = b*NU + u0 + du;
    float cn = f_*cbuf[ci] + i_*g_;
    cbuf[ci] = cn;
    float h = o_*tanh_(cn);
    u16 hi = f2b(h); hH[ci] = hi; hL[ci] = f2b(h - b2f(hi));
  }
}

// ---------------- phase B: q = h@W_q (blocks 0..63, hi-only) ; hWa = h@W_a[:1024] (64..127, hi/lo) ----------------
__global__ __launch_bounds__(512) void k_stepB(
    const u16* __restrict__ hHin, const u16* __restrict__ hLin,
    const u16* __restrict__ WqT,
    const u16* __restrict__ WaTH, const u16* __restrict__ WaTL,
    float* __restrict__ qf, float* __restrict__ hWaF)
{
  __shared__ float zs[8][32][16];
  int tid = threadIdx.x, lane = tid&63, wv = tid>>6;
  bool isQ = blockIdx.x < 64;
  int n0 = (blockIdx.x & 63)*16;
  int l15 = lane&15, ko = (lane>>4)*8;
  const u16* wh; const u16* wl = nullptr;
  if (isQ) wh = WqT + (size_t)(n0+l15)*1024;
  else { wh = WaTH + (size_t)(n0+l15)*2048; wl = WaTL + (size_t)(n0+l15)*2048; }
  f32x4 acc0 = {}, acc1 = {};
  #pragma unroll
  for (int ki=0; ki<4; ++ki){
    int kk = wv*128 + ki*32 + ko;
    bf16x8 a0h = *(const bf16x8*)(hHin + (size_t)l15*NU + kk);
    bf16x8 a1h = *(const bf16x8*)(hHin + (size_t)(l15+16)*NU + kk);
    bf16x8 a0l = *(const bf16x8*)(hLin + (size_t)l15*NU + kk);
    bf16x8 a1l = *(const bf16x8*)(hLin + (size_t)(l15+16)*NU + kk);
    bf16x8 bh = *(const bf16x8*)(wh + kk);
    if (isQ){
      acc0 = MFMA(a0l, bh, acc0, 0,0,0);
      acc0 = MFMA(a0h, bh, acc0, 0,0,0);
      acc1 = MFMA(a1l, bh, acc1, 0,0,0);
      acc1 = MFMA(a1h, bh, acc1, 0,0,0);
    } else {
      bf16x8 bl = *(const bf16x8*)(wl + kk);
      acc0 = MFMA(a0h, bl, acc0, 0,0,0);
      acc0 = MFMA(a0l, bh, acc0, 0,0,0);
      acc0 = MFMA(a0h, bh, acc0, 0,0,0);
      acc1 = MFMA(a1h, bl, acc1, 0,0,0);
      acc1 = MFMA(a1l, bh, acc1, 0,0,0);
      acc1 = MFMA(a1h, bh, acc1, 0,0,0);
    }
  }
  #pragma unroll
  for (int r=0; r<4; ++r){
    zs[wv][(lane>>4)*4 + r][l15]      = acc0[r];
    zs[wv][16 + (lane>>4)*4 + r][l15] = acc1[r];
  }
  __syncthreads();
  {
    int b = tid>>4, c = tid&15;
    float v = 0.f;
    #pragma unroll
    for (int w=0; w<8; ++w) v += zs[w][b][c];
    float* dst = isQ ? qf : hWaF;
    dst[b*NU + n0 + c] = v;
  }
}

// ---------------- phase C1: scores (128 blocks = 32 b x 4 s-chunks) ----------------
__global__ __launch_bounds__(256) void k_score(
    const u16* __restrict__ keysB, const float* __restrict__ qf,
    const float* __restrict__ v_att, float* __restrict__ scf)
{
  int b = blockIdx.x>>2, sq = blockIdx.x&3;
  int tid = threadIdx.x, lane = tid&63, wv = tid>>6;
  int a0 = lane*16;
  float qr[16], vr[16];
  #pragma unroll
  for (int j=0; j<4; ++j){
    *(float4*)&qr[j*4] = *(const float4*)(qf + b*NU + a0 + j*4);
    *(float4*)&vr[j*4] = *(const float4*)(v_att + a0 + j*4);
  }
  #pragma unroll
  for (int si=0; si<8; ++si){
    int s = sq*32 + wv*8 + si;
    const u16* kp = keysB + (size_t)(b*128 + s)*NU + a0;
    u16x8 k0 = *(const u16x8*)kp;
    u16x8 k1 = *(const u16x8*)(kp + 8);
    float p = 0.f;
    #pragma unroll
    for (int j=0; j<8; ++j) p += vr[j]   * tanh_(b2f(k0[j]) + qr[j]);
    #pragma unroll
    for (int j=0; j<8; ++j) p += vr[8+j] * tanh_(b2f(k1[j]) + qr[8+j]);
    #pragma unroll
    for (int off=32; off; off>>=1) p += __shfl_xor(p, off);
    if (lane==0) scf[b*128 + s] = p;
  }
}

// ---------------- phase C2: softmax + ctx chunk (128 blocks = 32 b x 4 col-chunks) ----------------
__global__ __launch_bounds__(256) void k_ctx(
    const float* __restrict__ scf, const u16* __restrict__ aB,
    u16* __restrict__ ctxH, u16* __restrict__ ctxL)
{
  __shared__ float alig[128];
  int b = blockIdx.x>>2, cq = blockIdx.x&3;
  int tid = threadIdx.x;
  if (tid < 64){
    float s0 = scf[b*128 + tid], s1 = scf[b*128 + 64 + tid];
    float m = fmaxf(s0, s1);
    #pragma unroll
    for (int off=32; off; off>>=1) m = fmaxf(m, __shfl_xor(m, off));
    float e0 = __expf(s0-m), e1 = __expf(s1-m);
    float sum = e0+e1;
    #pragma unroll
    for (int off=32; off; off>>=1) sum += __shfl_xor(sum, off);
    float inv = 1.f/sum;
    alig[tid] = e0*inv; alig[tid+64] = e1*inv;
  }
  __syncthreads();
  int col = cq*256 + tid;
  const u16* ap = aB + (size_t)b*128*NU + col;
  float acc = 0.f;
  #pragma unroll 8
  for (int s=0; s<128; ++s) acc += alig[s]*b2f(ap[(size_t)s*NU]);
  u16 hi = f2b(acc);
  ctxH[b*NU + col] = hi;
  ctxL[b*NU + col] = f2b(acc - b2f(hi));
}

// ---------------- phase D: attn = ctx@W_a[1024:] + hWa -> outs[t] ----------------
__global__ __launch_bounds__(512) void k_stepD(
    const u16* __restrict__ ctxH, const u16* __restrict__ ctxL,
    const u16* __restrict__ WaTH, const u16* __restrict__ WaTL,
    const float* __restrict__ hWaF,
    u16* __restrict__ outH, u16* __restrict__ outL, long sOut)
{
  __shared__ float zs[8][32][16];
  int tid = threadIdx.x, lane = tid&63, wv = tid>>6;
  int n0 = blockIdx.x*16;
  int l15 = lane&15, ko = (lane>>4)*8;
  const u16* wh = WaTH + (size_t)(n0+l15)*2048 + 1024;
  const u16* wl = WaTL + (size_t)(n0+l15)*2048 + 1024;
  f32x4 acc0 = {}, acc1 = {};
  #pragma unroll
  for (int ki=0; ki<4; ++ki){
    int kk = wv*128 + ki*32 + ko;
    bf16x8 a0h = *(const bf16x8*)(ctxH + (size_t)l15*NU + kk);
    bf16x8 a1h = *(const bf16x8*)(ctxH + (size_t)(l15+16)*NU + kk);
    bf16x8 a0l = *(const bf16x8*)(ctxL + (size_t)l15*NU + kk);
    bf16x8 a1l = *(const bf16x8*)(ctxL + (size_t)(l15+16)*NU + kk);
    bf16x8 bh = *(const bf16x8*)(wh + kk);
    bf16x8 bl = *(const bf16x8*)(wl + kk);
    acc0 = MFMA(a0h, bl, acc0, 0,0,0);
    acc0 = MFMA(a0l, bh, acc0, 0,0,0);
    acc0 = MFMA(a0h, bh, acc0, 0,0,0);
    acc1 = MFMA(a1h, bl, acc1, 0,0,0);
    acc1 = MFMA(a1l, bh, acc1, 0,0,0);
    acc1 = MFMA(a1h, bh, acc1, 0,0,0);
  }
  #pragma unroll
  for (int r=0; r<4; ++r){
    zs[wv][(lane>>4)*4 + r][l15]      = acc0[r];
    zs[wv][16 + (lane>>4)*4 + r][l15] = acc1[r];
  }
  __syncthreads();
  {
    int b = tid>>4, c = tid&15;
    float v = 0.f;
    #pragma unroll
    for (int w=0; w<8; ++w) v += zs[w][b][c];
    v += hWaF[b*NU + n0 + c];
    u16 hi = f2b(v);
    outH[(size_t)b*sOut + n0 + c] = hi;
    outL[(size_t)b*sOut + n0 + c] = f2b(v - b2f(hi));
  }
}

// ---------------- logits: 128x128-tile, BK=64, double-buffered reg-staged ----------------
#define LDSK 72
__global__ __launch_bounds__(256) void k_logits(
    const u16* __restrict__ A,   // [4096][1024] (rows >=4064 garbage, unused)
    const u16* __restrict__ Bt,  // [32000][1024]
    const float* __restrict__ bias,
    float* __restrict__ C)
{
  __shared__ __align__(16) u16 As[128*LDSK];
  __shared__ __align__(16) u16 Bs[128*LDSK];
  int tid = threadIdx.x, lane = tid&63, wv = tid>>6;
  int m0 = blockIdx.y*128, n0 = blockIdx.x*128;
  int wr = (wv>>1)*64, wc = (wv&1)*64;
  int l15 = lane&15, ko = (lane>>4)*8;
  int srow = tid>>3, sc8 = (tid&7)*8;
  f32x4 acc[4][4] = {};
  uint4 a0[4], b0[4], a1[4], b1[4];

  #define LOADG(ar, br, kk) { \
    _Pragma("unroll") \
    for (int i=0;i<4;++i){ \
      ar[i] = *(const uint4*)(A  + (size_t)(m0+srow+i*32)*1024 + (kk) + sc8); \
      br[i] = *(const uint4*)(Bt + (size_t)(n0+srow+i*32)*1024 + (kk) + sc8); \
    } }
  #define STORES(ar, br) { \
    _Pragma("unroll") \
    for (int i=0;i<4;++i){ \
      *(uint4*)(&As[(srow+i*32)*LDSK + sc8]) = ar[i]; \
      *(uint4*)(&Bs[(srow+i*32)*LDSK + sc8]) = br[i]; \
    } }
  #define COMPUTE() { \
    _Pragma("unroll") \
    for (int ks=0; ks<2; ++ks){ \
      bf16x8 af[4], bf[4]; \
      _Pragma("unroll") \
      for (int i=0;i<4;++i){ \
        af[i] = *(const bf16x8*)(&As[(wr+i*16+l15)*LDSK + ks*32 + ko]); \
        bf[i] = *(const bf16x8*)(&Bs[(wc+i*16+l15)*LDSK + ks*32 + ko]); \
      } \
      _Pragma("unroll") \
      for (int mi=0;mi<4;++mi) \
        _Pragma("unroll") \
        for (int ni=0;ni<4;++ni) \
          acc[mi][ni] = MFMA(af[mi], bf[ni], acc[mi][ni], 0,0,0); \
    } }

  LOADG(a0, b0, 0);
  for (int kk=0; kk<1024; kk+=128){
    __syncthreads();
    STORES(a0, b0);
    if (kk+64 < 1024) LOADG(a1, b1, kk+64);
    __syncthreads();
    COMPUTE();
    __syncthreads();
    STORES(a1, b1);
    if (kk+128 < 1024) LOADG(a0, b0, kk+128);
    __syncthreads();
    COMPUTE();
  }
  #pragma unroll
  for (int mi=0; mi<4; ++mi){
    int row = m0 + wr + mi*16 + (lane>>4)*4;
    #pragma unroll
    for (int ni=0; ni<4; ++ni){
      int col = n0 + wc + ni*16 + l15;
      float bval = bias[col];
      #pragma unroll
      for (int r=0; r<4; ++r){
        if (row + r < NB*NT)
          C[(size_t)(row+r)*NV + col] = acc[mi][ni][r] + bval;
      }
    }
  }
  #undef LOADG
  #undef STORES
  #undef COMPUTE
}

// ---------------- host ----------------
extern "C" void kernel_launch(void* const* d_in, const int* in_sizes, int n_in,
                              void* d_out, int out_size, void* d_ws, size_t ws_size,
                              hipStream_t stream)
{
  (void)in_sizes; (void)n_in; (void)out_size; (void)ws_size;
  const int*   toks  = (const int*)  d_in[0];
  const float* a_in  = (const float*)d_in[1];
  const float* a_tx  = (const float*)d_in[2];
  const float* c_tx  = (const float*)d_in[3];
  const float* emb   = (const float*)d_in[4];
  const float* W_k   = (const float*)d_in[5];
  const float* W_r   = (const float*)d_in[6];
  const float* bvec  = (const float*)d_in[7];
  const float* W_m   = (const float*)d_in[8];
  const float* W_q   = (const float*)d_in[9];
  const float* v_att = (const float*)d_in[10];
  const float* W_a   = (const float*)d_in[11];
  const float* W_o   = (const float*)d_in[12];
  const float* b_o   = (const float*)d_in[13];
  float* out = (float*)d_out;

  char* p = (char*)d_ws;
  auto alloc = [&](size_t bytes)->char*{ char* r = p; p += (bytes + 255) & ~(size_t)255; return r; };

  u16* WkrH = (u16*)alloc((size_t)4096*2048*2);
  u16* WkrL = (u16*)alloc((size_t)4096*2048*2);
  u16* WqH  = (u16*)alloc((size_t)1024*1024*2);
  u16* WaH  = (u16*)alloc((size_t)1024*2048*2);
  u16* WaL  = (u16*)alloc((size_t)1024*2048*2);
  u16* WmH  = (u16*)alloc((size_t)1024*1024*2);
  u16* WoH  = (u16*)alloc((size_t)NV*1024*2);
  u16* WkxH = (u16*)alloc((size_t)4096*256*2);
  u16* aB   = (u16*)alloc((size_t)NB*128*NU*2);
  u16* keysB= (u16*)alloc((size_t)NB*128*NU*2);
  u16* xB   = (u16*)alloc((size_t)NB*NT*NE*2);
  u16* xWb  = (u16*)alloc((size_t)NB*NT*4096*2);
  u16* outsH= (u16*)alloc((size_t)4096*NU*2);      // padded to 4096 rows for logits
  u16* outsL= (u16*)alloc((size_t)NB*NT*NU*2);
  u16* hH0  = (u16*)alloc((size_t)NB*NU*2);
  u16* hL0  = (u16*)alloc((size_t)NB*NU*2);
  u16* hH1  = (u16*)alloc((size_t)NB*NU*2);
  u16* hL1  = (u16*)alloc((size_t)NB*NU*2);
  u16* hiniH= (u16*)alloc((size_t)NB*NU*2);
  u16* hiniL= (u16*)alloc((size_t)NB*NU*2);
  u16* azero= (u16*)alloc((size_t)NB*NU*2);
  float* cbuf=(float*)alloc((size_t)NB*NU*4);
  float* qf  =(float*)alloc((size_t)NB*NU*4);
  float* hWaF=(float*)alloc((size_t)NB*NU*4);
  float* scf =(float*)alloc((size_t)NB*128*4);
  u16* ctxH = (u16*)alloc((size_t)NB*NU*2);
  u16* ctxL = (u16*)alloc((size_t)NB*NU*2);
  u16* hbH[2] = {hH0, hH1};
  u16* hbL[2] = {hL0, hL1};

  // ---- init & weight prep ----
  hipMemsetAsync(azero, 0, (size_t)NB*NU*2, stream);
  hipMemcpyAsync(cbuf, c_tx, (size_t)NB*NU*4, hipMemcpyDeviceToDevice, stream);
  k_split<<<128,256,0,stream>>>(a_tx, hiniH, hiniL, NB*NU);
  k_gather<<<(NB*NT*NE)/256,256,0,stream>>>(toks, emb, xB);
  k_conv<<<2048,256,0,stream>>>(a_in, aB, NB*128*NU);
  k_transpose<<<dim3(128,32),256,0,stream>>>(W_k + (size_t)256*4096, 4096, WkrH, WkrL, 2048, 0);
  k_transpose<<<dim3(128,32),256,0,stream>>>(W_r, 4096, WkrH, WkrL, 2048, 1024);
  k_transpose<<<dim3(32,32),256,0,stream>>>(W_q, 1024, WqH, nullptr, 1024, 0);
  k_transpose<<<dim3(32,64),256,0,stream>>>(W_a, 1024, WaH, WaL, 2048, 0);
  k_transpose<<<dim3(32,32),256,0,stream>>>(W_m, 1024, WmH, nullptr, 1024, 0);
  k_transpose<<<dim3(1000,32),256,0,stream>>>(W_o, NV, WoH, nullptr, 1024, 0);
  k_transpose<<<dim3(128,8),256,0,stream>>>(W_k, 4096, WkxH, nullptr, 256, 0);

  // keys = a @ W_m  (4096 x 1024, K=1024) -> bf16
  k_gemm64<1,0><<<dim3(16,64),256,0,stream>>>(aB, 1024, WmH, 1024, nullptr, keysB, 1024, nullptr, 4096, 1024);
  // xW = x @ W_k[0:256] + b  (4064 x 4096, K=256) -> bf16
  k_gemm64<1,1><<<dim3(64,64),256,0,stream>>>(xB, 256, WkxH, 256, nullptr, xWb, 4096, bvec, NB*NT, 256);

  // ---- recurrence ----
  for (int t=0; t<NT; ++t){
    const u16 *attnH, *attnL; long sAttn;
    if (t==0){ attnH = azero; attnL = azero; sAttn = NU; }
    else { attnH = outsH + (size_t)(t-1)*NU; attnL = outsL + (size_t)(t-1)*NU; sAttn = (long)NT*NU; }
    const u16* hinH = (t==0) ? hiniH : hbH[(t-1)&1];
    const u16* hinL = (t==0) ? hiniL : hbL[(t-1)&1];
    u16* houtH = hbH[t&1];
    u16* houtL = hbL[t&1];
    k_stepA<<<256,512,0,stream>>>(attnH, attnL, sAttn, hinH, hinL,
        WkrH, WkrL, xWb + (size_t)t*4096, (long)NT*4096, cbuf, houtH, houtL);
    k_stepB<<<128,512,0,stream>>>(houtH, houtL, WqH, WaH, WaL, qf, hWaF);
    k_score<<<128,256,0,stream>>>(keysB, qf, v_att, scf);
    k_ctx<<<128,256,0,stream>>>(scf, aB, ctxH, ctxL);
    k_stepD<<<64,512,0,stream>>>(ctxH, ctxL, WaH, WaL, hWaF,
        outsH + (size_t)t*NU, outsL + (size_t)t*NU, (long)NT*NU);
  }

  // ---- logits = outs @ W_o + b_o  (4064 x 32000, K=1024) ----
  k_logits<<<dim3(NV/128, 32),256,0,stream>>>(outsH, WoH, b_o, out);
}